// Round 14
// baseline (236.803 us; speedup 1.0000x reference)
//
#include <hip/hip_runtime.h>
#include <cstdint>
#include <cstddef>

typedef __attribute__((ext_vector_type(8))) short short8;
typedef __attribute__((ext_vector_type(4))) float f32x4;

typedef __attribute__((address_space(3))) unsigned int lds_u32;
typedef const __attribute__((address_space(1))) unsigned int glb_u32;

__device__ __forceinline__ void gl_lds16(const void* g, void* l) {
  __builtin_amdgcn_global_load_lds((glb_u32*)g, (lds_u32*)l, 16, 0, 0);
}

__device__ __forceinline__ unsigned short bf16_rne(float f) {
  unsigned int u = __float_as_uint(f);
  u += 0x7FFFu + ((u >> 16) & 1u);
  return (unsigned short)(u >> 16);
}

// ---------------- fused prep (unchanged from r13) ----------------------------
__device__ __forceinline__ void cvt_body(const float* __restrict__ in,
                                         unsigned short* __restrict__ out,
                                         int i, int n8) {
  if (i >= n8) return;
  float4 a = reinterpret_cast<const float4*>(in)[2 * i];
  float4 b = reinterpret_cast<const float4*>(in)[2 * i + 1];
  short8 v;
  v[0] = (short)bf16_rne(a.x); v[1] = (short)bf16_rne(a.y);
  v[2] = (short)bf16_rne(a.z); v[3] = (short)bf16_rne(a.w);
  v[4] = (short)bf16_rne(b.x); v[5] = (short)bf16_rne(b.y);
  v[6] = (short)bf16_rne(b.z); v[7] = (short)bf16_rne(b.w);
  reinterpret_cast<short8*>(out)[i] = v;
}

__global__ void __launch_bounds__(256) k_prep(const float* __restrict__ x,
                                              const float* __restrict__ mem,
                                              const float* __restrict__ Wq,
                                              const float* __restrict__ Wkv,
                                              const float* __restrict__ Wout,
                                              unsigned short* __restrict__ xb,
                                              unsigned short* __restrict__ mb,
                                              unsigned short* __restrict__ wqT,
                                              unsigned short* __restrict__ wkvT,
                                              unsigned short* __restrict__ woutT,
                                              unsigned short* __restrict__ pk,
                                              unsigned short* __restrict__ pv) {
  __shared__ float t[64][65];
  const int bid = blockIdx.x, tid = threadIdx.x;
  if (bid < 2048) {
    cvt_body(x, xb, bid * 256 + tid, 524288);
  } else if (bid < 8048) {
    cvt_body(mem, mb, (bid - 2048) * 256 + tid, 1536000);
  } else if (bid < 9072) {
    const float* W; unsigned short* WT; int R = 1024, C; int bid2, bx, by;
    if (bid < 8304)      { W = Wq;   WT = wqT;   C = 1024; bid2 = bid - 8048; bx = bid2 & 15; by = bid2 >> 4; }
    else if (bid < 8816) { W = Wkv;  WT = wkvT;  C = 2048; bid2 = bid - 8304; bx = bid2 & 31; by = bid2 >> 5; }
    else                 { W = Wout; WT = woutT; C = 1024; bid2 = bid - 8816; bx = bid2 & 15; by = bid2 >> 4; }
    const int c0 = bx * 64, r0 = by * 64;
    const int lr = tid >> 6, lc = tid & 63;
#pragma unroll
    for (int i = 0; i < 16; ++i)
      t[i * 4 + lr][lc] = W[(size_t)(r0 + i * 4 + lr) * C + c0 + lc];
    __syncthreads();
#pragma unroll
    for (int i = 0; i < 16; ++i) {
      int ro = i * 4 + lr;
      WT[(size_t)(c0 + ro) * R + r0 + lc] = bf16_rne(t[lc][ro]);
    }
  } else {
    int i = (bid - 9072) * 256 + tid;   // 128*36*64 = 294912
    if (i >= 128 * 36 * 64) return;
    int head = i / (36 * 64);
    int rem = i - head * (36 * 64);
    int t2 = rem / 64 + 1500;
    int dk = rem & 63;
    size_t ik = ((size_t)(head * 24 + 23) * 8 + (dk >> 3)) * 512 + (t2 & 63) * 8 + (dk & 7);
    size_t iv = ((size_t)(head * 24 + 23) * 8 + ((t2 >> 3) & 7)) * 512 + dk * 8 + (t2 & 7);
    pk[ik] = 0;
    pv[iv] = 0;
  }
}

// ---------------- 128x256 bf16 MFMA GEMM, BK=64, 3-buffer counted-vmcnt ------
// 512 threads = 8 waves (2M x 4N); per-wave output 64x64.
// Distance-2 pipeline: at K-step t stage t+2 into buf[(t+2)%3], compute from
// buf[t%3], then s_waitcnt vmcnt(6) (t+1's 6 stage-instrs landed; t+2's may
// remain in flight) + RAW s_barrier (no drain).  Safety: stage target != buffer
// being read this step or next (mod 3); reads of buf[t] complete before the
// end-of-t barrier (lgkm before MFMA); each barrier preceded by asm memory
// clobber so no memory op crosses it.
// MODE 0: q epilogue; MODE 1: kv epilogue (packed K/V); MODE 2: fp32 out.
template <int MODE>
__global__ void __launch_bounds__(512) k_gemm(const unsigned short* __restrict__ A,
                                              const unsigned short* __restrict__ BT,
                                              const float* __restrict__ bias,
                                              void* __restrict__ out1,
                                              void* __restrict__ out2,
                                              int M, int K) {
  __shared__ unsigned short As[3][128 * 64];
  __shared__ unsigned short Bs[3][256 * 64];
  const int tid = threadIdx.x;
  const int lane = tid & 63;
  const int wid = tid >> 6;
  const int grp = lane >> 4, lm = lane & 15;

  constexpr int NBY = (MODE == 1) ? 8 : 4;
  constexpr int NWG = (MODE == 1) ? 94 * 8 : 32 * 4;
  constexpr int CPX = NWG / 8;
  const int bid = blockIdx.x;
  const int logical = (bid & 7) * CPX + (bid >> 3);   // XCD-chunked (bijective)
  const int m0 = (logical / NBY) * 128, n0 = (logical % NBY) * 256;

  const int wm = (wid >> 2) * 64, wn = (wid & 3) * 64;
  const int srow = tid >> 3;                             // 0..63
  const int scolb = (tid & 7) * 16;                      // byte col 0..112

  constexpr int NKT = 16;   // K = 1024

#define STAGE(kt, buf)                                                        \
  {                                                                           \
    _Pragma("unroll") for (int j = 0; j < 2; ++j) {                           \
      int row = j * 64 + srow;                                                \
      int sxb = scolb ^ ((row & 7) << 4);                                     \
      int ra = m0 + row; if (ra > M - 1) ra = M - 1;                          \
      gl_lds16(A + (size_t)ra * K + (kt) * 64 + (sxb >> 1),                   \
               &As[buf][0] + j * 4096 + tid * 8);                             \
    }                                                                         \
    _Pragma("unroll") for (int j = 0; j < 4; ++j) {                           \
      int row = j * 64 + srow;                                                \
      int sxb = scolb ^ ((row & 7) << 4);                                     \
      gl_lds16(BT + (size_t)(n0 + row) * K + (kt) * 64 + (sxb >> 1),          \
               &Bs[buf][0] + j * 4096 + tid * 8);                             \
    }                                                                         \
  }

  f32x4 acc[4][4] = {};

  STAGE(0, 0);
  STAGE(1, 1);
  asm volatile("s_waitcnt vmcnt(6)" ::: "memory");
  __builtin_amdgcn_s_barrier();
  __builtin_amdgcn_sched_barrier(0);

  for (int t = 0; t < NKT; ++t) {
    const int cb = t % 3;
    if (t + 2 < NKT) {
      const int nb = (t + 2) % 3;
      if (nb == 0) STAGE(t + 2, 0) else if (nb == 1) STAGE(t + 2, 1) else STAGE(t + 2, 2);
    }

    short8 af[4][2], bfr[4][2];
#pragma unroll
    for (int m = 0; m < 4; ++m)
#pragma unroll
      for (int ks = 0; ks < 2; ++ks) {
        int row = wm + m * 16 + lm;
        int off = (ks * 64 + grp * 16) ^ ((row & 7) << 4);
        af[m][ks] = *reinterpret_cast<const short8*>(&As[cb][row * 64 + (off >> 1)]);
      }
#pragma unroll
    for (int n = 0; n < 4; ++n)
#pragma unroll
      for (int ks = 0; ks < 2; ++ks) {
        int row = wn + n * 16 + lm;
        int off = (ks * 64 + grp * 16) ^ ((row & 7) << 4);
        bfr[n][ks] = *reinterpret_cast<const short8*>(&Bs[cb][row * 64 + (off >> 1)]);
      }
#pragma unroll
    for (int m = 0; m < 4; ++m)
#pragma unroll
      for (int n = 0; n < 4; ++n)
#pragma unroll
        for (int ks = 0; ks < 2; ++ks)
          acc[m][n] = __builtin_amdgcn_mfma_f32_16x16x32_bf16(af[m][ks], bfr[n][ks],
                                                              acc[m][n], 0, 0, 0);

    if (t < NKT - 2) asm volatile("s_waitcnt vmcnt(6)" ::: "memory");
    else             asm volatile("s_waitcnt vmcnt(0)" ::: "memory");
    __builtin_amdgcn_s_barrier();
    __builtin_amdgcn_sched_barrier(0);
  }
#undef STAGE

#pragma unroll
  for (int m = 0; m < 4; ++m) {
    int rbase = m0 + wm + m * 16 + grp * 4;
#pragma unroll
    for (int n = 0; n < 4; ++n) {
      int cg = n0 + wn + n * 16 + lm;
      float bs = bias[cg];
#pragma unroll
      for (int r = 0; r < 4; ++r) {
        int row = rbase + r;
        float v = acc[m][n][r] + bs;
        if (MODE == 0) {
          v *= 0.180336884f;  // DK^-0.5 * log2(e)  (softmax runs in base-2)
          int b = row >> 9, t1 = row & 511, h = cg >> 6, dk = cg & 63;
          ((unsigned short*)out1)[(((size_t)b * 16 + h) * 512 + t1) * 64 + dk] = bf16_rne(v);
        } else if (MODE == 1) {
          if (row < M) {
            int b = row / 1500, t2 = row - b * 1500;
            if (cg < 1024) {
              int h = cg >> 6, dk = cg & 63;
              int head = b * 16 + h;
              size_t idx = ((size_t)(head * 24 + (t2 >> 6)) * 8 + (dk >> 3)) * 512 +
                           (t2 & 63) * 8 + (dk & 7);
              ((unsigned short*)out1)[idx] = bf16_rne(v);
            } else {
              int h = (cg - 1024) >> 6, dk = (cg - 1024) & 63;
              int head = b * 16 + h;
              size_t idx = ((size_t)(head * 24 + (t2 >> 6)) * 8 + ((t2 >> 3) & 7)) * 512 +
                           dk * 8 + (t2 & 7);
              ((unsigned short*)out2)[idx] = bf16_rne(v);
            }
          }
        } else {
          ((float*)out1)[(size_t)row * 1024 + cg] = v;
        }
      }
    }
  }
}

// ---------------- flash attention, split-KV x2 (unchanged from r13) ----------
__global__ void __launch_bounds__(256) k_attn(const unsigned short* __restrict__ Q,
                                              const unsigned short* __restrict__ PK,
                                              const unsigned short* __restrict__ PV,
                                              const int* __restrict__ mask,
                                              float* __restrict__ po,
                                              float* __restrict__ dn) {
  __shared__ unsigned short Ps[4][16 * 64];
  const int tid = threadIdx.x, lane = tid & 63, wid = tid >> 6;
  const int grp = lane >> 4, lm = lane & 15;
  const int bid = blockIdx.x;                       // 2048
  const int logical = (bid & 7) * 256 + (bid >> 3);
  const int head = logical >> 4, qt = (logical >> 1) & 7, half = logical & 1;
  const int b = head >> 4, h = head & 15;
  const int kt0 = half * 12;

  const unsigned short* qbase = Q + ((size_t)head * 512 + qt * 64) * 64;
  const unsigned short* kf = PK + (size_t)head * 98304 + grp * 512 + lm * 8;
  const unsigned short* vf = PV + (size_t)head * 98304 + grp * 512 + lm * 8;
  const int* mrow = mask + b * 1500;

  short8 aq[2];
#pragma unroll
  for (int ks = 0; ks < 2; ++ks)
    aq[ks] = *reinterpret_cast<const short8*>(qbase + (wid * 16 + lm) * 64 + ks * 32 + grp * 8);

  unsigned long long mlo = 0ull;
#pragma unroll
  for (int i = 0; i < 48; ++i) {
    int col = (kt0 + (i >> 2)) * 64 + (i & 3) * 16 + lm;
    unsigned int ok = (col < 1500) ? (mrow[col] != 0 ? 1u : 0u) : 0u;
    mlo |= (unsigned long long)ok << i;
  }

  f32x4 O[4] = {};
  f32x4 O4 = {0.f, 0.f, 0.f, 0.f};
  const short8 onesb = {(short)0x3F80, (short)0x3F80, (short)0x3F80, (short)0x3F80,
                        (short)0x3F80, (short)0x3F80, (short)0x3F80, (short)0x3F80};

  short8 bk[4][2];
#pragma unroll
  for (int n = 0; n < 4; ++n)
#pragma unroll
    for (int ks = 0; ks < 2; ++ks)
      bk[n][ks] = *reinterpret_cast<const short8*>(kf + (size_t)kt0 * 4096 + ks * 2048 + n * 128);

  for (int kt = kt0; kt < kt0 + 12; ++kt) {
    short8 bv[4][2];
#pragma unroll
    for (int n2 = 0; n2 < 4; ++n2)
#pragma unroll
      for (int ks = 0; ks < 2; ++ks)
        bv[n2][ks] = *reinterpret_cast<const short8*>(vf + (size_t)kt * 4096 + ks * 2048 + n2 * 128);

    f32x4 s[4];
#pragma unroll
    for (int n = 0; n < 4; ++n) {
      s[n] = f32x4{0.f, 0.f, 0.f, 0.f};
#pragma unroll
      for (int ks = 0; ks < 2; ++ks)
        s[n] = __builtin_amdgcn_mfma_f32_16x16x32_bf16(aq[ks], bk[n][ks], s[n], 0, 0, 0);
    }

    if (kt < kt0 + 11) {
#pragma unroll
      for (int n = 0; n < 4; ++n)
#pragma unroll
        for (int ks = 0; ks < 2; ++ks)
          bk[n][ks] = *reinterpret_cast<const short8*>(
              kf + (size_t)(kt + 1) * 4096 + ks * 2048 + n * 128);
    }

    unsigned int nib = (unsigned int)mlo & 15u;
    mlo >>= 4;
    float mb4[4];
#pragma unroll
    for (int n = 0; n < 4; ++n) mb4[n] = (nib >> n) & 1u ? -8.0f : -3.0e38f;
#pragma unroll
    for (int n = 0; n < 4; ++n)
#pragma unroll
      for (int r = 0; r < 4; ++r) s[n][r] = exp2f(s[n][r] + mb4[n]);

#pragma unroll
    for (int n = 0; n < 4; ++n)
#pragma unroll
      for (int r = 0; r < 4; ++r) {
        int prow = grp * 4 + r;
        int pb = (n * 16 + lm) * 2;
        Ps[wid][prow * 64 + ((pb ^ ((prow & 7) << 4)) >> 1)] = bf16_rne(s[n][r]);
      }
    short8 pa[2];
#pragma unroll
    for (int ks = 0; ks < 2; ++ks) {
      int off = (ks * 64 + grp * 16) ^ ((lm & 7) << 4);
      pa[ks] = *reinterpret_cast<const short8*>(&Ps[wid][lm * 64 + (off >> 1)]);
    }

#pragma unroll
    for (int n2 = 0; n2 < 4; ++n2)
#pragma unroll
      for (int ks = 0; ks < 2; ++ks)
        O[n2] = __builtin_amdgcn_mfma_f32_16x16x32_bf16(pa[ks], bv[n2][ks], O[n2], 0, 0, 0);
#pragma unroll
    for (int ks = 0; ks < 2; ++ks)
      O4 = __builtin_amdgcn_mfma_f32_16x16x32_bf16(pa[ks], onesb, O4, 0, 0, 0);
  }

  float* orow = po + (size_t)half * 4194304 +
                ((size_t)(b * 512 + qt * 64 + wid * 16 + grp * 4)) * 1024 + h * 64;
#pragma unroll
  for (int r = 0; r < 4; ++r)
#pragma unroll
    for (int n2 = 0; n2 < 4; ++n2)
      orow[r * 1024 + n2 * 16 + lm] = O[n2][r];
  if (lm == 0) {
    int t1g = b * 512 + qt * 64 + wid * 16 + grp * 4;
#pragma unroll
    for (int r = 0; r < 4; ++r)
      dn[half * 65536 + (t1g + r) * 16 + h] = O4[r];
  }
}

// ---------------- combine split-KV partials -> bf16 ctx (unchanged) ----------
__global__ void __launch_bounds__(256) k_comb(const float* __restrict__ po,
                                              const float* __restrict__ dn,
                                              unsigned short* __restrict__ ctx) {
  int idx = blockIdx.x * 256 + threadIdx.x;   // 524288 = 4096*128
  if (idx >= 524288) return;
  int row = idx >> 7, c8 = idx & 127;
  int col0 = c8 * 8, h = c8 >> 3;
  float d = dn[row * 16 + h] + dn[65536 + row * 16 + h];
  float inv = 1.0f / d;
  const float4* p0 = reinterpret_cast<const float4*>(po + (size_t)row * 1024 + col0);
  const float4* p1 = reinterpret_cast<const float4*>(po + 4194304 + (size_t)row * 1024 + col0);
  float4 a0 = p0[0], a1 = p0[1], b0 = p1[0], b1 = p1[1];
  short8 v;
  v[0] = (short)bf16_rne((a0.x + b0.x) * inv);
  v[1] = (short)bf16_rne((a0.y + b0.y) * inv);
  v[2] = (short)bf16_rne((a0.z + b0.z) * inv);
  v[3] = (short)bf16_rne((a0.w + b0.w) * inv);
  v[4] = (short)bf16_rne((a1.x + b1.x) * inv);
  v[5] = (short)bf16_rne((a1.y + b1.y) * inv);
  v[6] = (short)bf16_rne((a1.z + b1.z) * inv);
  v[7] = (short)bf16_rne((a1.w + b1.w) * inv);
  reinterpret_cast<short8*>(ctx)[idx] = v;
}

// ---------------- launch -----------------------------------------------------
extern "C" void kernel_launch(void* const* d_in, const int* in_sizes, int n_in,
                              void* d_out, int out_size, void* d_ws, size_t ws_size,
                              hipStream_t stream) {
  const float* x = (const float*)d_in[0];
  const float* mem = (const float*)d_in[1];
  const int* mask = (const int*)d_in[2];
  const float* Wq = (const float*)d_in[3];
  const float* bq = (const float*)d_in[4];
  const float* Wkv = (const float*)d_in[5];
  const float* bkv = (const float*)d_in[6];
  const float* Wout = (const float*)d_in[7];
  const float* bout = (const float*)d_in[8];

  uint8_t* w = (uint8_t*)d_ws;
  unsigned short* xb    = (unsigned short*)(w);               // 4096x1024  (dead after q-GEMM)
  unsigned short* mb    = (unsigned short*)(w + 8388608);     // 12000x1024 (dead after kv-GEMM)
  unsigned short* wqT   = (unsigned short*)(w + 32964608);    // dead after q-GEMM
  unsigned short* wkvT  = (unsigned short*)(w + 35061760);    // dead after kv-GEMM
  unsigned short* woutT = (unsigned short*)(w + 39256064);    // live until final GEMM
  unsigned short* qb    = (unsigned short*)(w + 41353216);    // q (B,H,512,64)
  unsigned short* kb    = (unsigned short*)(w + 49741824);    // packed K frags
  unsigned short* vtb   = (unsigned short*)(w + 74907648);    // packed V frags
  unsigned short* ctx   = (unsigned short*)(w + 100073472);   // 4096x1024
  float* po             = (float*)(w);                        // [2][4096][1024] fp32, 32MB
  float* dn             = (float*)(w + 33554432);             // [2][4096][16] fp32

  k_prep<<<10224, 256, 0, stream>>>(x, mem, Wq, Wkv, Wout, xb, mb, wqT, wkvT, woutT, kb, vtb);
  k_gemm<0><<<128, 512, 0, stream>>>(xb, wqT, bq, qb, nullptr, 4096, 1024);
  k_gemm<1><<<752, 512, 0, stream>>>(mb, wkvT, bkv, kb, vtb, 12000, 1024);
  k_attn<<<2048, 256, 0, stream>>>(qb, kb, vtb, mask, po, dn);
  k_comb<<<2048, 256, 0, stream>>>(po, dn, ctx);
  k_gemm<2><<<128, 512, 0, stream>>>(ctx, woutT, bout, d_out, nullptr, 4096, 1024);
}

// Round 16
// 229.323 us; speedup vs baseline: 1.0326x; 1.0326x over previous
//
#include <hip/hip_runtime.h>
#include <cstdint>
#include <cstddef>

typedef __attribute__((ext_vector_type(8))) short short8;
typedef __attribute__((ext_vector_type(4))) float f32x4;

typedef __attribute__((address_space(3))) unsigned int lds_u32;
typedef const __attribute__((address_space(1))) unsigned int glb_u32;

__device__ __forceinline__ void gl_lds16(const void* g, void* l) {
  __builtin_amdgcn_global_load_lds((glb_u32*)g, (lds_u32*)l, 16, 0, 0);
}

__device__ __forceinline__ unsigned short bf16_rne(float f) {
  unsigned int u = __float_as_uint(f);
  u += 0x7FFFu + ((u >> 16) & 1u);
  return (unsigned short)(u >> 16);
}

__device__ __forceinline__ short8 pack8(const float* v) {
  short8 r;
#pragma unroll
  for (int e = 0; e < 8; ++e) r[e] = (short)bf16_rne(v[e]);
  return r;
}

// ---------------- fused prep (unchanged from r13) ----------------------------
__device__ __forceinline__ void cvt_body(const float* __restrict__ in,
                                         unsigned short* __restrict__ out,
                                         int i, int n8) {
  if (i >= n8) return;
  float4 a = reinterpret_cast<const float4*>(in)[2 * i];
  float4 b = reinterpret_cast<const float4*>(in)[2 * i + 1];
  short8 v;
  v[0] = (short)bf16_rne(a.x); v[1] = (short)bf16_rne(a.y);
  v[2] = (short)bf16_rne(a.z); v[3] = (short)bf16_rne(a.w);
  v[4] = (short)bf16_rne(b.x); v[5] = (short)bf16_rne(b.y);
  v[6] = (short)bf16_rne(b.z); v[7] = (short)bf16_rne(b.w);
  reinterpret_cast<short8*>(out)[i] = v;
}

__global__ void __launch_bounds__(256) k_prep(const float* __restrict__ x,
                                              const float* __restrict__ mem,
                                              const float* __restrict__ Wq,
                                              const float* __restrict__ Wkv,
                                              const float* __restrict__ Wout,
                                              unsigned short* __restrict__ xb,
                                              unsigned short* __restrict__ mb,
                                              unsigned short* __restrict__ wqT,
                                              unsigned short* __restrict__ wkvT,
                                              unsigned short* __restrict__ woutT,
                                              unsigned short* __restrict__ pk,
                                              unsigned short* __restrict__ pv) {
  __shared__ float t[64][65];
  const int bid = blockIdx.x, tid = threadIdx.x;
  if (bid < 2048) {
    cvt_body(x, xb, bid * 256 + tid, 524288);
  } else if (bid < 8048) {
    cvt_body(mem, mb, (bid - 2048) * 256 + tid, 1536000);
  } else if (bid < 9072) {
    const float* W; unsigned short* WT; int R = 1024, C; int bid2, bx, by;
    if (bid < 8304)      { W = Wq;   WT = wqT;   C = 1024; bid2 = bid - 8048; bx = bid2 & 15; by = bid2 >> 4; }
    else if (bid < 8816) { W = Wkv;  WT = wkvT;  C = 2048; bid2 = bid - 8304; bx = bid2 & 31; by = bid2 >> 5; }
    else                 { W = Wout; WT = woutT; C = 1024; bid2 = bid - 8816; bx = bid2 & 15; by = bid2 >> 4; }
    const int c0 = bx * 64, r0 = by * 64;
    const int lr = tid >> 6, lc = tid & 63;
#pragma unroll
    for (int i = 0; i < 16; ++i)
      t[i * 4 + lr][lc] = W[(size_t)(r0 + i * 4 + lr) * C + c0 + lc];
    __syncthreads();
#pragma unroll
    for (int i = 0; i < 16; ++i) {
      int ro = i * 4 + lr;
      WT[(size_t)(c0 + ro) * R + r0 + lc] = bf16_rne(t[lc][ro]);
    }
  } else {
    int i = (bid - 9072) * 256 + tid;   // 128*36*64 = 294912
    if (i >= 128 * 36 * 64) return;
    int head = i / (36 * 64);
    int rem = i - head * (36 * 64);
    int t2 = rem / 64 + 1500;
    int dk = rem & 63;
    size_t ik = ((size_t)(head * 24 + 23) * 8 + (dk >> 3)) * 512 + (t2 & 63) * 8 + (dk & 7);
    size_t iv = ((size_t)(head * 24 + 23) * 8 + ((t2 >> 3) & 7)) * 512 + dk * 8 + (t2 & 7);
    pk[ik] = 0;
    pv[iv] = 0;
  }
}

// ---------------- 128x128 bf16 MFMA GEMM, BK=64, single-buffer gl_lds --------
// (r7 body — best measured: kv = 113 us)
// LDS image invariant: byte position P of a row holds logical element P ^ swz.
//   gl_lds path:   dest linear (lane col), source col = lane col ^ swz.
//   MODE 2 path:   SAME — dest linear As[row*64 + (tid&7)*8], source col
//                  (sxb>>1) = swizzled.  (r15 bug: dest was also swizzled ->
//                  identity image -> wrong fragments.  Rule #21.)
// MODE 0: q epilogue -> q bf16 (B,H,512,64) * (0.125*log2e)
// MODE 1: kv epilogue -> PACKED fragment-major K and V
// MODE 2: FUSED split-KV combine + out-GEMM; out1 = fp32 + bias.
template <int MODE>
__global__ void __launch_bounds__(256) k_gemm(const unsigned short* __restrict__ A,
                                              const unsigned short* __restrict__ BT,
                                              const float* __restrict__ bias,
                                              void* __restrict__ out1,
                                              void* __restrict__ out2,
                                              const float* __restrict__ po,
                                              const float* __restrict__ dn,
                                              int M, int K) {
  __shared__ unsigned short As[128 * 64];
  __shared__ unsigned short Bs[128 * 64];
  const int tid = threadIdx.x;
  const int lane = tid & 63;
  const int wid = tid >> 6;
  const int grp = lane >> 4, lm = lane & 15;

  constexpr int NBY = (MODE == 1) ? 16 : 8;
  constexpr int NWG = (MODE == 1) ? 94 * 16 : 32 * 8;
  constexpr int CPX = NWG / 8;
  const int bid = blockIdx.x;
  const int logical = (bid & 7) * CPX + (bid >> 3);   // XCD-chunked (bijective)
  const int m0 = (logical / NBY) * 128, n0 = (logical % NBY) * 128;

  const int wm = (wid >> 1) * 64, wn = (wid & 1) * 64;
  const int srow = tid >> 3;                            // 0..31

  f32x4 acc[4][4] = {};

  const int nkt = K >> 6;
  for (int kt = 0; kt < nkt; ++kt) {
    __syncthreads();   // prior iteration's fragment reads complete
#pragma unroll
    for (int c = 0; c < 4; ++c) {
      int row = c * 32 + srow;
      int sxb = ((tid & 7) * 16) ^ ((row & 7) << 4);   // swizzled SOURCE byte col
      if (MODE != 2) {
        int ra = m0 + row; if (ra > M - 1) ra = M - 1;
        gl_lds16(A + (size_t)ra * K + kt * 64 + (sxb >> 1), As + c * 2048 + tid * 8);
      } else {
        // fused combine: 8 fp32 from each split half -> bf16 fragment row.
        // dest LINEAR (lane col), source col swizzled — matches gl_lds image.
        int ra = m0 + row;
        float inv = 1.0f / (dn[ra * 16 + kt] + dn[65536 + ra * 16 + kt]);
        const float* p0 = po + (size_t)ra * 1024 + kt * 64 + (sxb >> 1);
        const float* p1 = p0 + 4194304;
        float4 x0 = *reinterpret_cast<const float4*>(p0);
        float4 x1 = *reinterpret_cast<const float4*>(p0 + 4);
        float4 y0 = *reinterpret_cast<const float4*>(p1);
        float4 y1 = *reinterpret_cast<const float4*>(p1 + 4);
        float v[8] = {(x0.x + y0.x) * inv, (x0.y + y0.y) * inv,
                      (x0.z + y0.z) * inv, (x0.w + y0.w) * inv,
                      (x1.x + y1.x) * inv, (x1.y + y1.y) * inv,
                      (x1.z + y1.z) * inv, (x1.w + y1.w) * inv};
        *reinterpret_cast<short8*>(&As[row * 64 + (tid & 7) * 8]) = pack8(v);
      }
      gl_lds16(BT + (size_t)(n0 + row) * K + kt * 64 + (sxb >> 1), Bs + c * 2048 + tid * 8);
    }
    __syncthreads();   // stage drained (vmcnt + lgkm) -> LDS ready

    short8 af[4][2], bfr[4][2];
#pragma unroll
    for (int m = 0; m < 4; ++m)
#pragma unroll
      for (int ks = 0; ks < 2; ++ks) {
        int row = wm + m * 16 + lm;
        int off = (ks * 64 + grp * 16) ^ ((row & 7) << 4);
        af[m][ks] = *reinterpret_cast<const short8*>(&As[row * 64 + (off >> 1)]);
      }
#pragma unroll
    for (int n = 0; n < 4; ++n)
#pragma unroll
      for (int ks = 0; ks < 2; ++ks) {
        int row = wn + n * 16 + lm;
        int off = (ks * 64 + grp * 16) ^ ((row & 7) << 4);
        bfr[n][ks] = *reinterpret_cast<const short8*>(&Bs[row * 64 + (off >> 1)]);
      }
#pragma unroll
    for (int m = 0; m < 4; ++m)
#pragma unroll
      for (int n = 0; n < 4; ++n)
#pragma unroll
        for (int ks = 0; ks < 2; ++ks)
          acc[m][n] = __builtin_amdgcn_mfma_f32_16x16x32_bf16(af[m][ks], bfr[n][ks],
                                                              acc[m][n], 0, 0, 0);
  }

#pragma unroll
  for (int m = 0; m < 4; ++m) {
    int rbase = m0 + wm + m * 16 + grp * 4;
#pragma unroll
    for (int n = 0; n < 4; ++n) {
      int cg = n0 + wn + n * 16 + lm;
      float bs = bias[cg];
#pragma unroll
      for (int r = 0; r < 4; ++r) {
        int row = rbase + r;
        float v = acc[m][n][r] + bs;
        if (MODE == 0) {
          v *= 0.180336884f;  // DK^-0.5 * log2(e)  (softmax runs in base-2)
          int b = row >> 9, t1 = row & 511, h = cg >> 6, dk = cg & 63;
          ((unsigned short*)out1)[(((size_t)b * 16 + h) * 512 + t1) * 64 + dk] = bf16_rne(v);
        } else if (MODE == 1) {
          if (row < M) {
            int b = row / 1500, t2 = row - b * 1500;
            if (cg < 1024) {
              int h = cg >> 6, dk = cg & 63;
              int head = b * 16 + h;
              size_t idx = ((size_t)(head * 24 + (t2 >> 6)) * 8 + (dk >> 3)) * 512 +
                           (t2 & 63) * 8 + (dk & 7);
              ((unsigned short*)out1)[idx] = bf16_rne(v);
            } else {
              int h = (cg - 1024) >> 6, dk = (cg - 1024) & 63;
              int head = b * 16 + h;
              size_t idx = ((size_t)(head * 24 + (t2 >> 6)) * 8 + ((t2 >> 3) & 7)) * 512 +
                           dk * 8 + (t2 & 7);
              ((unsigned short*)out2)[idx] = bf16_rne(v);
            }
          }
        } else {
          ((float*)out1)[(size_t)row * 1024 + cg] = v;
        }
      }
    }
  }
}

// ---------------- flash attention, split-KV x2 (unchanged from r13) ----------
__global__ void __launch_bounds__(256) k_attn(const unsigned short* __restrict__ Q,
                                              const unsigned short* __restrict__ PK,
                                              const unsigned short* __restrict__ PV,
                                              const int* __restrict__ mask,
                                              float* __restrict__ po,
                                              float* __restrict__ dn) {
  __shared__ unsigned short Ps[4][16 * 64];
  const int tid = threadIdx.x, lane = tid & 63, wid = tid >> 6;
  const int grp = lane >> 4, lm = lane & 15;
  const int bid = blockIdx.x;                       // 2048
  const int logical = (bid & 7) * 256 + (bid >> 3);
  const int head = logical >> 4, qt = (logical >> 1) & 7, half = logical & 1;
  const int b = head >> 4, h = head & 15;
  const int kt0 = half * 12;

  const unsigned short* qbase = Q + ((size_t)head * 512 + qt * 64) * 64;
  const unsigned short* kf = PK + (size_t)head * 98304 + grp * 512 + lm * 8;
  const unsigned short* vf = PV + (size_t)head * 98304 + grp * 512 + lm * 8;
  const int* mrow = mask + b * 1500;

  short8 aq[2];
#pragma unroll
  for (int ks = 0; ks < 2; ++ks)
    aq[ks] = *reinterpret_cast<const short8*>(qbase + (wid * 16 + lm) * 64 + ks * 32 + grp * 8);

  unsigned long long mlo = 0ull;
#pragma unroll
  for (int i = 0; i < 48; ++i) {
    int col = (kt0 + (i >> 2)) * 64 + (i & 3) * 16 + lm;
    unsigned int ok = (col < 1500) ? (mrow[col] != 0 ? 1u : 0u) : 0u;
    mlo |= (unsigned long long)ok << i;
  }

  f32x4 O[4] = {};
  f32x4 O4 = {0.f, 0.f, 0.f, 0.f};
  const short8 onesb = {(short)0x3F80, (short)0x3F80, (short)0x3F80, (short)0x3F80,
                        (short)0x3F80, (short)0x3F80, (short)0x3F80, (short)0x3F80};

  short8 bk[4][2];
#pragma unroll
  for (int n = 0; n < 4; ++n)
#pragma unroll
    for (int ks = 0; ks < 2; ++ks)
      bk[n][ks] = *reinterpret_cast<const short8*>(kf + (size_t)kt0 * 4096 + ks * 2048 + n * 128);

  for (int kt = kt0; kt < kt0 + 12; ++kt) {
    short8 bv[4][2];
#pragma unroll
    for (int n2 = 0; n2 < 4; ++n2)
#pragma unroll
      for (int ks = 0; ks < 2; ++ks)
        bv[n2][ks] = *reinterpret_cast<const short8*>(vf + (size_t)kt * 4096 + ks * 2048 + n2 * 128);

    f32x4 s[4];
#pragma unroll
    for (int n = 0; n < 4; ++n) {
      s[n] = f32x4{0.f, 0.f, 0.f, 0.f};
#pragma unroll
      for (int ks = 0; ks < 2; ++ks)
        s[n] = __builtin_amdgcn_mfma_f32_16x16x32_bf16(aq[ks], bk[n][ks], s[n], 0, 0, 0);
    }

    if (kt < kt0 + 11) {
#pragma unroll
      for (int n = 0; n < 4; ++n)
#pragma unroll
        for (int ks = 0; ks < 2; ++ks)
          bk[n][ks] = *reinterpret_cast<const short8*>(
              kf + (size_t)(kt + 1) * 4096 + ks * 2048 + n * 128);
    }

    unsigned int nib = (unsigned int)mlo & 15u;
    mlo >>= 4;
    float mb4[4];
#pragma unroll
    for (int n = 0; n < 4; ++n) mb4[n] = (nib >> n) & 1u ? -8.0f : -3.0e38f;
#pragma unroll
    for (int n = 0; n < 4; ++n)
#pragma unroll
      for (int r = 0; r < 4; ++r) s[n][r] = exp2f(s[n][r] + mb4[n]);

#pragma unroll
    for (int n = 0; n < 4; ++n)
#pragma unroll
      for (int r = 0; r < 4; ++r) {
        int prow = grp * 4 + r;
        int pb = (n * 16 + lm) * 2;
        Ps[wid][prow * 64 + ((pb ^ ((prow & 7) << 4)) >> 1)] = bf16_rne(s[n][r]);
      }
    short8 pa[2];
#pragma unroll
    for (int ks = 0; ks < 2; ++ks) {
      int off = (ks * 64 + grp * 16) ^ ((lm & 7) << 4);
      pa[ks] = *reinterpret_cast<const short8*>(&Ps[wid][lm * 64 + (off >> 1)]);
    }

#pragma unroll
    for (int n2 = 0; n2 < 4; ++n2)
#pragma unroll
      for (int ks = 0; ks < 2; ++ks)
        O[n2] = __builtin_amdgcn_mfma_f32_16x16x32_bf16(pa[ks], bv[n2][ks], O[n2], 0, 0, 0);
#pragma unroll
    for (int ks = 0; ks < 2; ++ks)
      O4 = __builtin_amdgcn_mfma_f32_16x16x32_bf16(pa[ks], onesb, O4, 0, 0, 0);
  }

  float* orow = po + (size_t)half * 4194304 +
                ((size_t)(b * 512 + qt * 64 + wid * 16 + grp * 4)) * 1024 + h * 64;
#pragma unroll
  for (int r = 0; r < 4; ++r)
#pragma unroll
    for (int n2 = 0; n2 < 4; ++n2)
      orow[r * 1024 + n2 * 16 + lm] = O[n2][r];
  if (lm == 0) {
    int t1g = b * 512 + qt * 64 + wid * 16 + grp * 4;
#pragma unroll
    for (int r = 0; r < 4; ++r)
      dn[half * 65536 + (t1g + r) * 16 + h] = O4[r];
  }
}

// ---------------- launch -----------------------------------------------------
extern "C" void kernel_launch(void* const* d_in, const int* in_sizes, int n_in,
                              void* d_out, int out_size, void* d_ws, size_t ws_size,
                              hipStream_t stream) {
  const float* x = (const float*)d_in[0];
  const float* mem = (const float*)d_in[1];
  const int* mask = (const int*)d_in[2];
  const float* Wq = (const float*)d_in[3];
  const float* bq = (const float*)d_in[4];
  const float* Wkv = (const float*)d_in[5];
  const float* bkv = (const float*)d_in[6];
  const float* Wout = (const float*)d_in[7];
  const float* bout = (const float*)d_in[8];

  uint8_t* w = (uint8_t*)d_ws;
  unsigned short* xb    = (unsigned short*)(w);               // 4096x1024  (dead after q-GEMM)
  unsigned short* mb    = (unsigned short*)(w + 8388608);     // 12000x1024 (dead after kv-GEMM)
  unsigned short* wqT   = (unsigned short*)(w + 32964608);    // dead after q-GEMM
  unsigned short* wkvT  = (unsigned short*)(w + 35061760);    // dead after kv-GEMM
  unsigned short* woutT = (unsigned short*)(w + 39256064);    // live until final GEMM
  unsigned short* qb    = (unsigned short*)(w + 41353216);    // q (B,H,512,64)
  unsigned short* kb    = (unsigned short*)(w + 49741824);    // packed K frags
  unsigned short* vtb   = (unsigned short*)(w + 74907648);    // packed V frags
  float* po             = (float*)(w);                        // [2][4096][1024] fp32, 32MB (overlays dead xb/mb/wqT)
  float* dn             = (float*)(w + 33554432);             // [2][4096][16] fp32 (overlays dead wqT/wkvT)

  k_prep<<<10224, 256, 0, stream>>>(x, mem, Wq, Wkv, Wout, xb, mb, wqT, wkvT, woutT, kb, vtb);
  k_gemm<0><<<256, 256, 0, stream>>>(xb, wqT, bq, qb, nullptr, nullptr, nullptr, 4096, 1024);
  k_gemm<1><<<1504, 256, 0, stream>>>(mb, wkvT, bkv, kb, vtb, nullptr, nullptr, 12000, 1024);
  k_attn<<<2048, 256, 0, stream>>>(qb, kb, vtb, mask, po, dn);
  k_gemm<2><<<256, 256, 0, stream>>>(nullptr, woutT, bout, d_out, nullptr, po, dn, 4096, 1024);
}